// Round 7
// baseline (511.244 us; speedup 1.0000x reference)
//
#include <hip/hip_runtime.h>
#include <hip/hip_fp16.h>

#define N_NODES 25000
#define N_EDGES 400000
#define EPS_F 1e-5f

typedef _Float16 f16x8 __attribute__((ext_vector_type(8)));
typedef _Float16 f16x4 __attribute__((ext_vector_type(4)));
typedef float    f32x4 __attribute__((ext_vector_type(4)));

__device__ __forceinline__ float silu_f(float x) {
    return x / (1.0f + __expf(-x));
}

// ---------------------------------------------------------------------------
// K0: pre-pack Wfc1/2/3 into MFMA A-fragment order (f16) in global ws.
// Consumer reads gA*[ (tile*64 + lane)*8 ] as f16x8 (coalesced 16 B/lane).
// gA1: 4 tiles (K=8 real, rest zero). gA2: 8 tiles (ks*4+nt). gA3: 28 (ks*14+nt).
// ---------------------------------------------------------------------------
__global__ __launch_bounds__(256) void k_prepack(
    const float* __restrict__ Wfc1, const float* __restrict__ Wfc2,
    const float* __restrict__ Wfc3,
    _Float16* __restrict__ gA1, _Float16* __restrict__ gA2,
    _Float16* __restrict__ gA3)
{
    int t = blockIdx.x * 256 + threadIdx.x;
    int L = t & 63, q = L >> 4, cc = L & 15;
    if (t < 256) {
        int nt = t >> 6;
        f16x8 p;
#pragma unroll
        for (int j = 0; j < 8; ++j)
            p[j] = (q == 0) ? (_Float16)Wfc1[j*64 + nt*16 + cc] : (_Float16)0.f;
        *(f16x8*)&gA1[t*8] = p;
    } else if (t < 768) {
        int tt = t - 256;
        int tile = tt >> 6, ks = tile >> 2, nt = tile & 3;
        int kb = ks*32 + q*8;
        f16x8 p;
#pragma unroll
        for (int j = 0; j < 8; ++j)
            p[j] = (_Float16)Wfc2[(kb+j)*64 + nt*16 + cc];
        *(f16x8*)&gA2[tt*8] = p;
    } else if (t < 2560) {
        int tt = t - 768;
        int tile = tt >> 6, ks = tile / 14, nt = tile - ks*14;
        int kb = ks*32 + q*8;
        f16x8 p;
#pragma unroll
        for (int j = 0; j < 8; ++j)
            p[j] = (_Float16)Wfc3[(kb+j)*224 + nt*16 + cc];
        *(f16x8*)&gA3[tt*8] = p;
    }
}

// ---------------------------------------------------------------------------
// K1: per-node linear transforms, WAVE-per-node. Lane j computes output
// channel j; inputs broadcast via shfl; weight reads coalesced, L1-resident.
// BUGFIX vs R6: hi lanes (c=2 channels) must shuffle vz from lanes 32..63 —
// source lane is u | (lane & 32), not u (which gave them vx).
// XS/SC row layout (stride 192 f32): [0..63]=s, [64 + v*4 + c]=v (c<3, pad).
// ---------------------------------------------------------------------------
__global__ __launch_bounds__(256) void k_node_pre(
    const float* __restrict__ nh,
    const float* __restrict__ W1_0, const float* __restrict__ W1_1,
    const float* __restrict__ Wsc0, const float* __restrict__ Wsc1,
    float* __restrict__ XS, float* __restrict__ SC)
{
    int lane = threadIdx.x & 63, wv = threadIdx.x >> 6;
    int n = blockIdx.x*4 + wv;
    if (n >= N_NODES) return;
    int u_ = lane & 31;
    bool lo = lane < 32;
    const float* row = nh + n*160;

    float sval = row[lane];                    // s_in[k], lane=k
    float vx = row[64 + u_*3 + 0];
    float vy = row[64 + u_*3 + 1];
    float vz = row[64 + u_*3 + 2];

    // ---- scalar: out[j] = sum_k s[k] * W[k][j] ----
    float as = 0.f, bs = 0.f;
#pragma unroll 4
    for (int k = 0; k < 64; ++k) {
        float sk = __shfl(sval, k);
        as += sk * W1_0[k*64 + lane];
        bs += sk * Wsc0[k*64 + lane];
    }
    float* xsrow = XS + n*192;
    float* scrow = SC + n*192;
    xsrow[lane] = as * 0.125f;                 // 1/sqrt(64)
    scrow[lane] = bs * 0.125f;

    // ---- vector: out[v][c] = sum_u v[u][c] * W[u][v] ----
    // lo lanes: (v=u_, c=0 and c=1); hi lanes: (v=u_, c=2)
    float selv = lo ? vx : vz;
    int srcbase = lane & 32;                   // hi lanes source vz from 32..63
    float aP=0.f, aQ=0.f, bP=0.f, bQ=0.f;
#pragma unroll 4
    for (int u = 0; u < 32; ++u) {
        float su = __shfl(selv, u | srcbase);  // vx[u] (lo) / vz[u] (hi)
        float sy = __shfl(vy, u);
        float wa = W1_1[u*32 + u_];
        float wb = Wsc1[u*32 + u_];
        aP += su*wa; aQ += sy*wa;
        bP += su*wb; bQ += sy*wb;
    }
    const float is32 = 0.17677669529663687f;   // 1/sqrt(32)
    if (lo) {
        xsrow[64 + u_*4 + 0] = aP * is32;
        xsrow[64 + u_*4 + 1] = aQ * is32;
        scrow[64 + u_*4 + 0] = bP * is32;
        scrow[64 + u_*4 + 1] = bQ * is32;
    } else {
        xsrow[64 + u_*4 + 2] = aP * is32;
        scrow[64 + u_*4 + 2] = bP * is32;
    }
}

// ---------------------------------------------------------------------------
// K2: per-src edge lists. Only int atomics (400k).
// ---------------------------------------------------------------------------
__global__ __launch_bounds__(256) void k_build_lists(
    const int* __restrict__ ei, int* __restrict__ CNT, int* __restrict__ LIST)
{
    int e = blockIdx.x * 256 + threadIdx.x;
    if (e >= N_EDGES) return;
    int src = ei[e];                       // row 0 = edge_src
    int pos = atomicAdd(&CNT[src], 1);
    if (pos < 64) LIST[src*64 + pos] = e;
}

// ---------------------------------------------------------------------------
// K3 (FUSED): per node-wave: gather edge attrs -> 3-layer MFMA MLP on 16-edge
// tiles (R5-verified fragment scheme: D = W^T·h^T, col=edge, row=channel) ->
// w-tile in wave-private LDS -> tensor product + segment sum in registers ->
// output GEMMs + RMS norms. WE intermediate ELIMINATED (-358 MB HBM).
// Barrier-free: every LDS region is wave-private. A-frags from pre-packed
// global (L1/L2-resident, coalesced). Global prefetch chain spans tiles.
// ---------------------------------------------------------------------------
__global__ __launch_bounds__(256, 2) void k_fused(
    const int* __restrict__ ei, const float* __restrict__ esh,
    const float* __restrict__ eat,
    const _Float16* __restrict__ gA1, const _Float16* __restrict__ gA2,
    const _Float16* __restrict__ gA3,
    const float* __restrict__ XS, const float* __restrict__ SC,
    const int* __restrict__ CNT, const int* __restrict__ LIST,
    const float* __restrict__ W2_0, const float* __restrict__ W2_1,
    const float* __restrict__ g0, const float* __restrict__ g1,
    float* __restrict__ out)
{
    __shared__ _Float16 avb[64*40];     //  5 KB  attrs f16, cols 8..31 zero
    __shared__ _Float16 h1b[64*72];     //  9 KB
    __shared__ _Float16 h2b[64*72];     //  9 KB
    __shared__ _Float16 wt [64*228];    // 28.5 KB  w-tiles [16 edges x 224+pad]
    __shared__ float aS[4][96];         //  1.5 KB
    __shared__ float aV[4][392];        //  6 KB   [c*130 + row]
    // total 60.5 KB -> 2 blocks/CU

    const int tid = threadIdx.x;
    const int lane = tid & 63, wv = tid >> 6;
    const int q = lane >> 4, col = lane & 15;
    const int u_ = lane & 31;
    const bool lo = lane < 32;
    const int erow = wv*16 + col;

    int n = blockIdx.x*4 + wv;
    if (n >= N_NODES) return;            // wave-uniform; kernel has no barriers

    int cnt = CNT[n]; cnt = cnt > 64 ? 64 : cnt;
    const int* edst = ei + N_EDGES;

    int e_l = 0, dst_l = 0;
    if (cnt > 0) {
        int li = lane < cnt ? lane : cnt - 1;
        e_l = LIST[n*64 + li];
        dst_l = edst[e_l];
    }

    // zero avb pad cols (k=8..31) for this wave's 16 rows, once
    {
        int off0 = lane * 3;
#pragma unroll
        for (int z = 0; z < 3; ++z) {
            int off = off0 + z;          // 0..191
            int r12 = off / 12, s2 = off - r12*12;
            *(unsigned int*)&avb[(wv*16 + r12)*40 + 8 + s2*2] = 0u;
        }
    }

    float accM0=0, aV0x=0, aV0y=0, aV0z=0, accM1=0, a12x=0, a12y=0, a12z=0;

    // global prefetch chain (esh, sd, vv) — independent of tile structure
    float4 sh_c = make_float4(0,0,0,0), vv_c = sh_c;
    float sd_c = 0;
    if (cnt > 0) {
        int e = __shfl(e_l, 0), dst = __shfl(dst_l, 0);
        sh_c = *(const float4*)(esh + e*4);
        const float* xd = XS + dst*192;
        sd_c = xd[lane];
        vv_c = *(const float4*)(xd + 64 + u_*4);
    }

    const float IS8 = 0.35355339059327373f;   // 1/sqrt(8)
    int ntiles = (cnt + 15) >> 4;
    int i = 0;
#pragma unroll 1
    for (int t = 0; t < ntiles; ++t) {
        // ---- stage tile's 16 edges x 8 attrs -> avb (wave-private) ----
        {
            int idx = t*16 + (lane >> 1);
            if (idx >= cnt) idx = cnt - 1;       // duplicate last (finite, unused)
            int egv = __shfl(e_l, idx);
            if (lo) {
                int part = lane & 1;
                float4 v = *(const float4*)(eat + egv*8 + part*4);
                f16x4 p; p[0]=(_Float16)v.x; p[1]=(_Float16)v.y;
                         p[2]=(_Float16)v.z; p[3]=(_Float16)v.w;
                *(f16x4*)&avb[(wv*16 + (lane>>1))*40 + part*4] = p;
            }
        }
        // ---- layer 1: 8 -> 64 (K zero-padded to 32), silu ----
        f16x8 b1 = *(const f16x8*)&avb[erow*40 + q*8];
#pragma unroll
        for (int nt = 0; nt < 4; ++nt) {
            f32x4 acc = {0.f,0.f,0.f,0.f};
            f16x8 a = *(const f16x8*)&gA1[(nt*64 + lane)*8];
            acc = __builtin_amdgcn_mfma_f32_16x16x32_f16(a, b1, acc, 0, 0, 0);
            f16x4 p;
#pragma unroll
            for (int r = 0; r < 4; ++r) p[r] = (_Float16)silu_f(acc[r]*IS8);
            *(f16x4*)&h1b[erow*72 + nt*16 + q*4] = p;
        }
        // ---- layer 2: 64 -> 64, silu ----
#pragma unroll
        for (int nt = 0; nt < 4; ++nt) {
            f32x4 acc = {0.f,0.f,0.f,0.f};
#pragma unroll
            for (int ks = 0; ks < 2; ++ks) {
                f16x8 a = *(const f16x8*)&gA2[((ks*4+nt)*64 + lane)*8];
                f16x8 b = *(const f16x8*)&h1b[erow*72 + ks*32 + q*8];
                acc = __builtin_amdgcn_mfma_f32_16x16x32_f16(a, b, acc, 0, 0, 0);
            }
            f16x4 p;
#pragma unroll
            for (int r = 0; r < 4; ++r) p[r] = (_Float16)silu_f(acc[r]*0.125f);
            *(f16x4*)&h2b[erow*72 + nt*16 + q*4] = p;
        }
        // ---- layer 3: 64 -> 224 -> wave-private w-tile ----
#pragma unroll 1
        for (int nt = 0; nt < 14; ++nt) {
            f32x4 acc = {0.f,0.f,0.f,0.f};
#pragma unroll
            for (int ks = 0; ks < 2; ++ks) {
                f16x8 a = *(const f16x8*)&gA3[((ks*14+nt)*64 + lane)*8];
                f16x8 b = *(const f16x8*)&h2b[erow*72 + ks*32 + q*8];
                acc = __builtin_amdgcn_mfma_f32_16x16x32_f16(a, b, acc, 0, 0, 0);
            }
            f16x4 p;
#pragma unroll
            for (int r = 0; r < 4; ++r) p[r] = (_Float16)(acc[r]*0.125f);
            *(f16x4*)&wt[erow*228 + nt*16 + q*4] = p;
        }
        // ---- tensor product over this tile's edges (w from LDS) ----
        int tc = cnt - t*16; if (tc > 16) tc = 16;
#pragma unroll 1
        for (int j = 0; j < tc; ++j, ++i) {
            float4 sh = sh_c, vv = vv_c;
            float sd = sd_c;
            if (i + 1 < cnt) {
                int e = __shfl(e_l, i+1), dst = __shfl(dst_l, i+1);
                sh_c = *(const float4*)(esh + e*4);
                const float* xd = XS + dst*192;
                sd_c = xd[lane];
                vv_c = *(const float4*)(xd + 64 + u_*4);
            }
            const _Float16* wr = &wt[(wv*16 + j)*228];
            float w0 = (float)wr[lane];
            float w1 = (float)wr[64 + lane];
            float wA = (float)wr[(lo ? 128 : 192) + u_];
            float w3 = (float)wr[160 + u_];
            accM0 += w0*sd*sh.x;                              // m0
            float t1 = w1*sd;                                 // mv0
            aV0x += t1*sh.y; aV0y += t1*sh.z; aV0z += t1*sh.w;
            if (lo) {
                accM1 += w3*(vv.x*sh.y + vv.y*sh.z + vv.z*sh.w);   // m1
                a12x += wA*vv.x*sh.x; a12y += wA*vv.y*sh.x; a12z += wA*vv.z*sh.x; // mv1
            } else {                                           // mv2: w4*cross(vd,sh1)
                a12x += wA*(vv.y*sh.w - vv.z*sh.z);
                a12y += wA*(vv.z*sh.y - vv.x*sh.w);
                a12z += wA*(vv.x*sh.z - vv.y*sh.y);
            }
        }
    }

    const float SEG = 0.25f;                    // 1/sqrt(16)
    const float IS3 = 0.5773502691896258f;      // 1/sqrt(3)
    const float IS2 = 0.7071067811865476f;      // 1/sqrt(2)
    aS[wv][lane] = accM0 * SEG;
    aV[wv][0*130 + lane] = aV0x * SEG;
    aV[wv][1*130 + lane] = aV0y * SEG;
    aV[wv][2*130 + lane] = aV0z * SEG;
    if (lo) {
        aS[wv][64 + u_] = accM1 * SEG * IS3;
        aV[wv][0*130 + 64 + u_] = a12x * SEG;
        aV[wv][1*130 + 64 + u_] = a12y * SEG;
        aV[wv][2*130 + 64 + u_] = a12z * SEG;
    } else {
        aV[wv][0*130 + 96 + u_] = a12x * SEG * IS2;
        aV[wv][1*130 + 96 + u_] = a12y * SEG * IS2;
        aV[wv][2*130 + 96 + u_] = a12z * SEG * IS2;
    }
    // no barrier: epilogue reads only this wave's aS/aV rows

    // out_s = ns @ W2_0 / sqrt(96) + sc_s
    float o0=0,o1=0,o2=0,o3=0;
#pragma unroll 4
    for (int k = 0; k < 96; k += 4) {
        o0 += aS[wv][k+0] * W2_0[(k+0)*64 + lane];
        o1 += aS[wv][k+1] * W2_0[(k+1)*64 + lane];
        o2 += aS[wv][k+2] * W2_0[(k+2)*64 + lane];
        o3 += aS[wv][k+3] * W2_0[(k+3)*64 + lane];
    }
    float os = (o0+o1)+(o2+o3);
    const float IS96 = 0.10206207261596575f;  // 1/sqrt(96)
    os = os*IS96 + SC[n*192 + lane];

    // out_v[v][c] = sum_u nv[u][c] * W2_1[u][v] / sqrt(128) + sc_v
    int coff = lo ? 0 : 2*130;
    float p0=0,p1=0,q0=0,q1=0;
#pragma unroll 4
    for (int u = 0; u < 128; u += 2) {
        float wv0 = W2_1[(u+0)*32 + u_];
        float wv1 = W2_1[(u+1)*32 + u_];
        p0 += aV[wv][coff + u+0]*wv0;  q0 += aV[wv][130 + u+0]*wv0;
        p1 += aV[wv][coff + u+1]*wv1;  q1 += aV[wv][130 + u+1]*wv1;
    }
    float ov0 = p0+p1, ov1 = q0+q1;
    const float IS128 = 0.08838834764831845f; // 1/sqrt(128)
    float4 scv = *(const float4*)(SC + n*192 + 64 + u_*4);
    float x0 = ov0*IS128 + (lo ? scv.x : scv.z);
    float x1 = ov1*IS128 + scv.y;

    float r = os*os;
#pragma unroll
    for (int off = 32; off > 0; off >>= 1) r += __shfl_xor(r, off);
    float rms_s = sqrtf(r*(1.0f/64.0f) + EPS_F);
    float rv = lo ? (x0*x0 + x1*x1) : (x0*x0);
#pragma unroll
    for (int off = 32; off > 0; off >>= 1) rv += __shfl_xor(rv, off);
    float rms_v = sqrtf(rv*(1.0f/32.0f) + EPS_F);

    float* orow = out + n*160;
    orow[lane] = os / rms_s * g0[lane];
    float gv = g1[u_] / rms_v;
    if (lo) {
        orow[64 + u_*3 + 0] = x0 * gv;
        orow[64 + u_*3 + 1] = x1 * gv;
    } else {
        orow[64 + u_*3 + 2] = x0 * gv;
    }
}

// ---------------------------------------------------------------------------
extern "C" void kernel_launch(void* const* d_in, const int* in_sizes, int n_in,
                              void* d_out, int out_size, void* d_ws, size_t ws_size,
                              hipStream_t stream)
{
    const float* nh   = (const float*)d_in[0];
    const int*   ei   = (const int*)  d_in[1];
    const float* esh  = (const float*)d_in[2];
    const float* eat  = (const float*)d_in[3];
    const float* W1_0 = (const float*)d_in[4];
    const float* W1_1 = (const float*)d_in[5];
    const float* Wfc1 = (const float*)d_in[6];
    const float* Wfc2 = (const float*)d_in[7];
    const float* Wfc3 = (const float*)d_in[8];
    const float* W2_0 = (const float*)d_in[9];
    const float* W2_1 = (const float*)d_in[10];
    const float* Wsc0 = (const float*)d_in[11];
    const float* Wsc1 = (const float*)d_in[12];
    const float* g0   = (const float*)d_in[13];
    const float* g1   = (const float*)d_in[14];
    float* out = (float*)d_out;

    // workspace layout — ~45 MiB
    char* base = (char*)d_ws;
    float*    XS   = (float*)base;                             // N*192 f32  19.2 MB
    float*    SC   = XS + (size_t)N_NODES*192;                 // N*192 f32  19.2 MB
    _Float16* gA1  = (_Float16*)(SC + (size_t)N_NODES*192);    // 2048 f16
    _Float16* gA2  = gA1 + 2048;                               // 4096 f16
    _Float16* gA3  = gA2 + 4096;                               // 14336 f16
    int*      CNT  = (int*)(gA3 + 14336);                      // N int
    int*      LIST = CNT + N_NODES;                            // N*64 int    6.4 MB

    hipMemsetAsync(CNT, 0, N_NODES*sizeof(int), stream);
    k_prepack   <<<10, 256, 0, stream>>>(Wfc1, Wfc2, Wfc3, gA1, gA2, gA3);
    k_node_pre  <<<(N_NODES+3)/4, 256, 0, stream>>>(nh, W1_0, W1_1, Wsc0, Wsc1, XS, SC);
    k_build_lists<<<(N_EDGES+255)/256, 256, 0, stream>>>(ei, CNT, LIST);
    k_fused     <<<(N_NODES+3)/4, 256, 0, stream>>>(ei, esh, eat, gA1, gA2, gA3,
                                                    XS, SC, CNT, LIST,
                                                    W2_0, W2_1, g0, g1, out);
}

// Round 8
// 387.984 us; speedup vs baseline: 1.3177x; 1.3177x over previous
//
#include <hip/hip_runtime.h>
#include <hip/hip_fp16.h>

#define N_NODES 25000
#define N_EDGES 400000
#define EPS_F 1e-5f
#define EPB 256   // edges per block in k_edge_mlp (4 chunks of 64)

typedef _Float16 f16x8 __attribute__((ext_vector_type(8)));
typedef _Float16 f16x4 __attribute__((ext_vector_type(4)));
typedef float    f32x4 __attribute__((ext_vector_type(4)));

__device__ __forceinline__ float silu_f(float x) {
    return x / (1.0f + __expf(-x));
}

// ---------------------------------------------------------------------------
// K0: pre-pack Wfc1/2/3 into MFMA A-fragment order (f16) in global ws.
// (R7-verified layout.) Consumer reads gA*[(tile*64+lane)*8] as f16x8.
// ---------------------------------------------------------------------------
__global__ __launch_bounds__(256) void k_prepack(
    const float* __restrict__ Wfc1, const float* __restrict__ Wfc2,
    const float* __restrict__ Wfc3,
    _Float16* __restrict__ gA1, _Float16* __restrict__ gA2,
    _Float16* __restrict__ gA3)
{
    int t = blockIdx.x * 256 + threadIdx.x;
    int L = t & 63, q = L >> 4, cc = L & 15;
    if (t < 256) {
        int nt = t >> 6;
        f16x8 p;
#pragma unroll
        for (int j = 0; j < 8; ++j)
            p[j] = (q == 0) ? (_Float16)Wfc1[j*64 + nt*16 + cc] : (_Float16)0.f;
        *(f16x8*)&gA1[t*8] = p;
    } else if (t < 768) {
        int tt = t - 256;
        int tile = tt >> 6, ks = tile >> 2, nt = tile & 3;
        int kb = ks*32 + q*8;
        f16x8 p;
#pragma unroll
        for (int j = 0; j < 8; ++j)
            p[j] = (_Float16)Wfc2[(kb+j)*64 + nt*16 + cc];
        *(f16x8*)&gA2[tt*8] = p;
    } else if (t < 2560) {
        int tt = t - 768;
        int tile = tt >> 6, ks = tile / 14, nt = tile - ks*14;
        int kb = ks*32 + q*8;
        f16x8 p;
#pragma unroll
        for (int j = 0; j < 8; ++j)
            p[j] = (_Float16)Wfc3[(kb+j)*224 + nt*16 + cc];
        *(f16x8*)&gA3[tt*8] = p;
    }
}

// ---------------------------------------------------------------------------
// K1: per-node linear transforms, WAVE-per-node (R7-verified incl. the
// srcbase shuffle fix). XS/SC row: [0..63]=s, [64+v*4+c]=v (c<3, pad).
// ---------------------------------------------------------------------------
__global__ __launch_bounds__(256) void k_node_pre(
    const float* __restrict__ nh,
    const float* __restrict__ W1_0, const float* __restrict__ W1_1,
    const float* __restrict__ Wsc0, const float* __restrict__ Wsc1,
    float* __restrict__ XS, float* __restrict__ SC)
{
    int lane = threadIdx.x & 63, wv = threadIdx.x >> 6;
    int n = blockIdx.x*4 + wv;
    if (n >= N_NODES) return;
    int u_ = lane & 31;
    bool lo = lane < 32;
    const float* row = nh + n*160;

    float sval = row[lane];
    float vx = row[64 + u_*3 + 0];
    float vy = row[64 + u_*3 + 1];
    float vz = row[64 + u_*3 + 2];

    float as = 0.f, bs = 0.f;
#pragma unroll 4
    for (int k = 0; k < 64; ++k) {
        float sk = __shfl(sval, k);
        as += sk * W1_0[k*64 + lane];
        bs += sk * Wsc0[k*64 + lane];
    }
    float* xsrow = XS + n*192;
    float* scrow = SC + n*192;
    xsrow[lane] = as * 0.125f;
    scrow[lane] = bs * 0.125f;

    float selv = lo ? vx : vz;
    int srcbase = lane & 32;                   // hi lanes source vz from 32..63
    float aP=0.f, aQ=0.f, bP=0.f, bQ=0.f;
#pragma unroll 4
    for (int u = 0; u < 32; ++u) {
        float su = __shfl(selv, u | srcbase);
        float sy = __shfl(vy, u);
        float wa = W1_1[u*32 + u_];
        float wb = Wsc1[u*32 + u_];
        aP += su*wa; aQ += sy*wa;
        bP += su*wb; bQ += sy*wb;
    }
    const float is32 = 0.17677669529663687f;
    if (lo) {
        xsrow[64 + u_*4 + 0] = aP * is32;
        xsrow[64 + u_*4 + 1] = aQ * is32;
        scrow[64 + u_*4 + 0] = bP * is32;
        scrow[64 + u_*4 + 1] = bQ * is32;
    } else {
        xsrow[64 + u_*4 + 2] = aP * is32;
        scrow[64 + u_*4 + 2] = bP * is32;
    }
}

// ---------------------------------------------------------------------------
// K2: per-src edge lists. Only int atomics (400k).
// ---------------------------------------------------------------------------
__global__ __launch_bounds__(256) void k_build_lists(
    const int* __restrict__ ei, int* __restrict__ CNT, int* __restrict__ LIST)
{
    int e = blockIdx.x * 256 + threadIdx.x;
    if (e >= N_EDGES) return;
    int src = ei[e];
    int pos = atomicAdd(&CNT[src], 1);
    if (pos < 64) LIST[src*64 + pos] = e;
}

// ---------------------------------------------------------------------------
// K3: edge MLP via fp16 MFMA (R5-verified body) with A-fragments from
// pre-packed GLOBAL gA (R7-verified addressing) instead of 40-KB LDS staging:
// LDS 63->23 KB so residency rises ~3x (the R5 version was occupancy-capped
// at 2 blocks/CU; MFMA floor for this kernel is ~8 us).
// WE row-major [e][224] f16, packed f16x4 stores.
// ---------------------------------------------------------------------------
__global__ __launch_bounds__(256) void k_edge_mlp(
    const float* __restrict__ eat,
    const _Float16* __restrict__ gA1, const _Float16* __restrict__ gA2,
    const _Float16* __restrict__ gA3,
    _Float16* __restrict__ WE)
{
    __shared__ _Float16 avb[64*40];     //  5 KB  attrs f16, cols 8..31 zero
    __shared__ _Float16 h1b[64*72];     //  9 KB
    __shared__ _Float16 h2b[64*72];     //  9 KB

    const int tid  = threadIdx.x;
    const int lane = tid & 63, wv = tid >> 6;
    const int q = lane >> 4, col = lane & 15;
    const int erow = wv*16 + col;

    // zero avb pad cols (k=8..31) once per block
    for (int idx = tid; idx < 64*12; idx += 256) {
        int e = idx / 12, s = idx - e*12;
        *(unsigned int*)&avb[e*40 + 8 + s*2] = 0u;
    }

    const float IS8 = 0.35355339059327373f;  // 1/sqrt(8)
    size_t base = (size_t)blockIdx.x * EPB;

#pragma unroll 1
    for (int c = 0; c < EPB/64; ++c) {
        size_t cb = base + (size_t)c*64;
        __syncthreads();                     // prior chunk's avb readers done
        if (tid < 128) {                     // stage 64 edges x 8 attrs -> f16
            int e = tid >> 1, part = tid & 1;
            size_t eg = cb + e; if (eg >= N_EDGES) eg = N_EDGES - 1;
            float4 v = *(const float4*)(eat + eg*8 + part*4);
            f16x4 p; p[0]=(_Float16)v.x; p[1]=(_Float16)v.y;
                     p[2]=(_Float16)v.z; p[3]=(_Float16)v.w;
            *(f16x4*)&avb[e*40 + part*4] = p;
        }
        __syncthreads();

        // ---- layer 1: 8 -> 64 (K zero-padded to 32), silu ----
        f16x8 b1 = *(const f16x8*)&avb[erow*40 + q*8];
#pragma unroll
        for (int nt = 0; nt < 4; ++nt) {
            f32x4 acc = {0.f,0.f,0.f,0.f};
            f16x8 a = *(const f16x8*)&gA1[(nt*64 + lane)*8];
            acc = __builtin_amdgcn_mfma_f32_16x16x32_f16(a, b1, acc, 0, 0, 0);
            f16x4 p;
#pragma unroll
            for (int r = 0; r < 4; ++r) p[r] = (_Float16)silu_f(acc[r]*IS8);
            *(f16x4*)&h1b[erow*72 + nt*16 + q*4] = p;   // wave-private rows
        }
        // ---- layer 2: 64 -> 64, silu ----
#pragma unroll
        for (int nt = 0; nt < 4; ++nt) {
            f32x4 acc = {0.f,0.f,0.f,0.f};
#pragma unroll
            for (int ks = 0; ks < 2; ++ks) {
                f16x8 a = *(const f16x8*)&gA2[((ks*4+nt)*64 + lane)*8];
                f16x8 b = *(const f16x8*)&h1b[erow*72 + ks*32 + q*8];
                acc = __builtin_amdgcn_mfma_f32_16x16x32_f16(a, b, acc, 0, 0, 0);
            }
            f16x4 p;
#pragma unroll
            for (int r = 0; r < 4; ++r) p[r] = (_Float16)silu_f(acc[r]*0.125f);
            *(f16x4*)&h2b[erow*72 + nt*16 + q*4] = p;
        }
        // ---- layer 3: 64 -> 224, packed f16x4 global stores ----
        size_t eg = cb + erow;
        bool wrb = eg < N_EDGES;
#pragma unroll 1
        for (int nt = 0; nt < 14; ++nt) {
            f32x4 acc = {0.f,0.f,0.f,0.f};
#pragma unroll
            for (int ks = 0; ks < 2; ++ks) {
                f16x8 a = *(const f16x8*)&gA3[((ks*14+nt)*64 + lane)*8];
                f16x8 b = *(const f16x8*)&h2b[erow*72 + ks*32 + q*8];
                acc = __builtin_amdgcn_mfma_f32_16x16x32_f16(a, b, acc, 0, 0, 0);
            }
            f16x4 p;
#pragma unroll
            for (int r = 0; r < 4; ++r) p[r] = (_Float16)(acc[r]*0.125f);
            if (wrb) *(f16x4*)&WE[eg*224 + nt*16 + q*4] = p;
        }
    }
}

// ---------------------------------------------------------------------------
// K4: wave-per-node gather + tensor product + segment sum (R5-verified math),
// now with a 2-slot software pipeline (~14 loads in flight/wave instead of 7;
// R5 counters: VALUBusy 53% = latency gaps, pure VALU floor is ~9 us).
// ---------------------------------------------------------------------------
struct Pref { float4 sh, vv; float sd; unsigned short w0, w1, wA, w3; };

__device__ __forceinline__ void preload(
    Pref& P, int e, int dst,
    const float* __restrict__ esh, const _Float16* __restrict__ WE,
    const float* __restrict__ XS, int lane, int u_, bool lo)
{
    P.sh = *(const float4*)(esh + (size_t)e*4);
    const _Float16* wr = WE + (size_t)e*224;
    P.w0 = *(const unsigned short*)(wr + lane);
    P.w1 = *(const unsigned short*)(wr + 64 + lane);
    P.wA = *(const unsigned short*)(wr + (lo ? 128 : 192) + u_);
    P.w3 = *(const unsigned short*)(wr + 160 + u_);
    const float* xd = XS + (size_t)dst*192;
    P.sd = xd[lane];
    P.vv = *(const float4*)(xd + 64 + u_*4);
}

__global__ __launch_bounds__(256) void k_aggregate(
    const int* __restrict__ ei, const float* __restrict__ esh,
    const _Float16* __restrict__ WE, const float* __restrict__ XS,
    const float* __restrict__ SC, const int* __restrict__ CNT,
    const int* __restrict__ LIST,
    const float* __restrict__ W2_0, const float* __restrict__ W2_1,
    const float* __restrict__ g0, const float* __restrict__ g1,
    float* __restrict__ out)
{
    __shared__ float aS[4][96];
    __shared__ float aV[4][392];   // [c*130 + row]
    int tid = threadIdx.x;
    int lane = tid & 63, wave = tid >> 6;
    int n = blockIdx.x*4 + wave;
    bool act = n < N_NODES;
    int u_ = lane & 31;
    bool lo = lane < 32;

    float accM0=0, aV0x=0, aV0y=0, aV0z=0, accM1=0, a12x=0, a12y=0, a12z=0;
    int cnt = 0;
    if (act) { int c = CNT[n]; cnt = c > 64 ? 64 : c; }
    const int* edst = ei + N_EDGES;

    int e_l = 0, dst_l = 0;
    if (act && cnt > 0) {
        int li = lane < cnt ? lane : cnt - 1;
        e_l = LIST[n*64 + li];
        dst_l = edst[e_l];
    }

    Pref P0, P1;
    if (cnt > 0) preload(P0, __shfl(e_l,0), __shfl(dst_l,0), esh, WE, XS, lane, u_, lo);
    if (cnt > 1) preload(P1, __shfl(e_l,1), __shfl(dst_l,1), esh, WE, XS, lane, u_, lo);

#pragma unroll 1
    for (int i = 0; i < cnt; i += 2) {
        {
            Pref cur = P0;
            if (i + 2 < cnt)
                preload(P0, __shfl(e_l,i+2), __shfl(dst_l,i+2), esh, WE, XS, lane, u_, lo);
            float w0 = (float)*(const _Float16*)&cur.w0;
            float w1 = (float)*(const _Float16*)&cur.w1;
            float wA = (float)*(const _Float16*)&cur.wA;
            float w3 = (float)*(const _Float16*)&cur.w3;
            accM0 += w0*cur.sd*cur.sh.x;
            float t1 = w1*cur.sd;
            aV0x += t1*cur.sh.y; aV0y += t1*cur.sh.z; aV0z += t1*cur.sh.w;
            if (lo) {
                accM1 += w3*(cur.vv.x*cur.sh.y + cur.vv.y*cur.sh.z + cur.vv.z*cur.sh.w);
                a12x += wA*cur.vv.x*cur.sh.x; a12y += wA*cur.vv.y*cur.sh.x; a12z += wA*cur.vv.z*cur.sh.x;
            } else {
                a12x += wA*(cur.vv.y*cur.sh.w - cur.vv.z*cur.sh.z);
                a12y += wA*(cur.vv.z*cur.sh.y - cur.vv.x*cur.sh.w);
                a12z += wA*(cur.vv.x*cur.sh.z - cur.vv.y*cur.sh.y);
            }
        }
        if (i + 1 < cnt) {
            Pref cur = P1;
            if (i + 3 < cnt)
                preload(P1, __shfl(e_l,i+3), __shfl(dst_l,i+3), esh, WE, XS, lane, u_, lo);
            float w0 = (float)*(const _Float16*)&cur.w0;
            float w1 = (float)*(const _Float16*)&cur.w1;
            float wA = (float)*(const _Float16*)&cur.wA;
            float w3 = (float)*(const _Float16*)&cur.w3;
            accM0 += w0*cur.sd*cur.sh.x;
            float t1 = w1*cur.sd;
            aV0x += t1*cur.sh.y; aV0y += t1*cur.sh.z; aV0z += t1*cur.sh.w;
            if (lo) {
                accM1 += w3*(cur.vv.x*cur.sh.y + cur.vv.y*cur.sh.z + cur.vv.z*cur.sh.w);
                a12x += wA*cur.vv.x*cur.sh.x; a12y += wA*cur.vv.y*cur.sh.x; a12z += wA*cur.vv.z*cur.sh.x;
            } else {
                a12x += wA*(cur.vv.y*cur.sh.w - cur.vv.z*cur.sh.z);
                a12y += wA*(cur.vv.z*cur.sh.y - cur.vv.x*cur.sh.w);
                a12z += wA*(cur.vv.x*cur.sh.z - cur.vv.y*cur.sh.y);
            }
        }
    }

    const float SEG = 0.25f;                    // 1/sqrt(16)
    const float IS3 = 0.5773502691896258f;      // 1/sqrt(3)
    const float IS2 = 0.7071067811865476f;      // 1/sqrt(2)
    if (act) {
        aS[wave][lane] = accM0 * SEG;
        aV[wave][0*130 + lane] = aV0x * SEG;
        aV[wave][1*130 + lane] = aV0y * SEG;
        aV[wave][2*130 + lane] = aV0z * SEG;
        if (lo) {
            aS[wave][64 + u_] = accM1 * SEG * IS3;
            aV[wave][0*130 + 64 + u_] = a12x * SEG;
            aV[wave][1*130 + 64 + u_] = a12y * SEG;
            aV[wave][2*130 + 64 + u_] = a12z * SEG;
        } else {
            aV[wave][0*130 + 96 + u_] = a12x * SEG * IS2;
            aV[wave][1*130 + 96 + u_] = a12y * SEG * IS2;
            aV[wave][2*130 + 96 + u_] = a12z * SEG * IS2;
        }
    }
    __syncthreads();
    if (!act) return;

    // out_s = ns @ W2_0 / sqrt(96) + sc_s
    float o0=0,o1=0,o2=0,o3=0;
#pragma unroll 4
    for (int k = 0; k < 96; k += 4) {
        o0 += aS[wave][k+0] * W2_0[(k+0)*64 + lane];
        o1 += aS[wave][k+1] * W2_0[(k+1)*64 + lane];
        o2 += aS[wave][k+2] * W2_0[(k+2)*64 + lane];
        o3 += aS[wave][k+3] * W2_0[(k+3)*64 + lane];
    }
    float os = (o0+o1)+(o2+o3);
    const float IS96 = 0.10206207261596575f;  // 1/sqrt(96)
    os = os*IS96 + SC[n*192 + lane];

    // out_v[v][c] = sum_u nv[u][c] * W2_1[u][v] / sqrt(128) + sc_v
    int coff = lo ? 0 : 2*130;
    float p0=0,p1=0,q0=0,q1=0;
#pragma unroll 4
    for (int u = 0; u < 128; u += 2) {
        float wv0 = W2_1[(u+0)*32 + u_];
        float wv1 = W2_1[(u+1)*32 + u_];
        p0 += aV[wave][coff + u+0]*wv0;  q0 += aV[wave][130 + u+0]*wv0;
        p1 += aV[wave][coff + u+1]*wv1;  q1 += aV[wave][130 + u+1]*wv1;
    }
    float ov0 = p0+p1, ov1 = q0+q1;
    const float IS128 = 0.08838834764831845f; // 1/sqrt(128)
    float4 scv = *(const float4*)(SC + n*192 + 64 + u_*4);
    float x0 = ov0*IS128 + (lo ? scv.x : scv.z);
    float x1 = ov1*IS128 + scv.y;

    float r = os*os;
#pragma unroll
    for (int off = 32; off > 0; off >>= 1) r += __shfl_xor(r, off);
    float rms_s = sqrtf(r*(1.0f/64.0f) + EPS_F);
    float rv = lo ? (x0*x0 + x1*x1) : (x0*x0);
#pragma unroll
    for (int off = 32; off > 0; off >>= 1) rv += __shfl_xor(rv, off);
    float rms_v = sqrtf(rv*(1.0f/32.0f) + EPS_F);

    float* orow = out + n*160;
    orow[lane] = os / rms_s * g0[lane];
    float gv = g1[u_] / rms_v;
    if (lo) {
        orow[64 + u_*3 + 0] = x0 * gv;
        orow[64 + u_*3 + 1] = x1 * gv;
    } else {
        orow[64 + u_*3 + 2] = x0 * gv;
    }
}

// ---------------------------------------------------------------------------
extern "C" void kernel_launch(void* const* d_in, const int* in_sizes, int n_in,
                              void* d_out, int out_size, void* d_ws, size_t ws_size,
                              hipStream_t stream)
{
    const float* nh   = (const float*)d_in[0];
    const int*   ei   = (const int*)  d_in[1];
    const float* esh  = (const float*)d_in[2];
    const float* eat  = (const float*)d_in[3];
    const float* W1_0 = (const float*)d_in[4];
    const float* W1_1 = (const float*)d_in[5];
    const float* Wfc1 = (const float*)d_in[6];
    const float* Wfc2 = (const float*)d_in[7];
    const float* Wfc3 = (const float*)d_in[8];
    const float* W2_0 = (const float*)d_in[9];
    const float* W2_1 = (const float*)d_in[10];
    const float* Wsc0 = (const float*)d_in[11];
    const float* Wsc1 = (const float*)d_in[12];
    const float* g0   = (const float*)d_in[13];
    const float* g1   = (const float*)d_in[14];
    float* out = (float*)d_out;

    // workspace layout — ~214 MiB
    char* base = (char*)d_ws;
    float*    XS   = (float*)base;                             // N*192 f32   19.2 MB
    float*    SC   = XS + (size_t)N_NODES*192;                 // N*192 f32   19.2 MB
    _Float16* WE   = (_Float16*)(SC + (size_t)N_NODES*192);    // E*224 f16  179.2 MB
    _Float16* gA1  = WE + (size_t)N_EDGES*224;                 // 2048 f16
    _Float16* gA2  = gA1 + 2048;                               // 4096 f16
    _Float16* gA3  = gA2 + 4096;                               // 14336 f16
    int*      CNT  = (int*)(gA3 + 14336);                      // N int
    int*      LIST = CNT + N_NODES;                            // N*64 int     6.4 MB

    hipMemsetAsync(CNT, 0, N_NODES*sizeof(int), stream);
    k_prepack   <<<10, 256, 0, stream>>>(Wfc1, Wfc2, Wfc3, gA1, gA2, gA3);
    k_node_pre  <<<(N_NODES+3)/4, 256, 0, stream>>>(nh, W1_0, W1_1, Wsc0, Wsc1, XS, SC);
    k_build_lists<<<(N_EDGES+255)/256, 256, 0, stream>>>(ei, CNT, LIST);
    k_edge_mlp  <<<(N_EDGES+EPB-1)/EPB, 256, 0, stream>>>(eat, gA1, gA2, gA3, WE);
    k_aggregate <<<(N_NODES+3)/4, 256, 0, stream>>>(ei, esh, WE, XS, SC, CNT, LIST,
                                                    W2_0, W2_1, g0, g1, out);
}

// Round 9
// 369.050 us; speedup vs baseline: 1.3853x; 1.0513x over previous
//
#include <hip/hip_runtime.h>
#include <hip/hip_fp16.h>

#define N_NODES 25000
#define N_EDGES 400000
#define EPS_F 1e-5f

typedef _Float16 f16x8 __attribute__((ext_vector_type(8)));
typedef _Float16 f16x4 __attribute__((ext_vector_type(4)));
typedef float    f32x4 __attribute__((ext_vector_type(4)));
typedef unsigned int uint;

__device__ __forceinline__ float silu_f(float x) {
    return x / (1.0f + __expf(-x));
}

// ---------------------------------------------------------------------------
// K0: pre-pack Wfc1/2/3 into MFMA A-fragment order (f16) in global ws.
// (R7/R8-verified layout.) Consumer reads gA*[(tile*64+lane)*8] as f16x8.
// ---------------------------------------------------------------------------
__global__ __launch_bounds__(256) void k_prepack(
    const float* __restrict__ Wfc1, const float* __restrict__ Wfc2,
    const float* __restrict__ Wfc3,
    _Float16* __restrict__ gA1, _Float16* __restrict__ gA2,
    _Float16* __restrict__ gA3)
{
    int t = blockIdx.x * 256 + threadIdx.x;
    int L = t & 63, q = L >> 4, cc = L & 15;
    if (t < 256) {
        int nt = t >> 6;
        f16x8 p;
#pragma unroll
        for (int j = 0; j < 8; ++j)
            p[j] = (q == 0) ? (_Float16)Wfc1[j*64 + nt*16 + cc] : (_Float16)0.f;
        *(f16x8*)&gA1[t*8] = p;
    } else if (t < 768) {
        int tt = t - 256;
        int tile = tt >> 6, ks = tile >> 2, nt = tile & 3;
        int kb = ks*32 + q*8;
        f16x8 p;
#pragma unroll
        for (int j = 0; j < 8; ++j)
            p[j] = (_Float16)Wfc2[(kb+j)*64 + nt*16 + cc];
        *(f16x8*)&gA2[tt*8] = p;
    } else if (t < 2560) {
        int tt = t - 768;
        int tile = tt >> 6, ks = tile / 14, nt = tile - ks*14;
        int kb = ks*32 + q*8;
        f16x8 p;
#pragma unroll
        for (int j = 0; j < 8; ++j)
            p[j] = (_Float16)Wfc3[(kb+j)*224 + nt*16 + cc];
        *(f16x8*)&gA3[tt*8] = p;
    }
}

// ---------------------------------------------------------------------------
// K1: per-node linear transforms, WAVE-per-node (R7/R8-verified).
// XS/SC row: [0..63]=s, [64+v*4+c]=v (c<3, pad).
// ---------------------------------------------------------------------------
__global__ __launch_bounds__(256) void k_node_pre(
    const float* __restrict__ nh,
    const float* __restrict__ W1_0, const float* __restrict__ W1_1,
    const float* __restrict__ Wsc0, const float* __restrict__ Wsc1,
    float* __restrict__ XS, float* __restrict__ SC)
{
    int lane = threadIdx.x & 63, wv = threadIdx.x >> 6;
    int n = blockIdx.x*4 + wv;
    if (n >= N_NODES) return;
    int u_ = lane & 31;
    bool lo = lane < 32;
    const float* row = nh + n*160;

    float sval = row[lane];
    float vx = row[64 + u_*3 + 0];
    float vy = row[64 + u_*3 + 1];
    float vz = row[64 + u_*3 + 2];

    float as = 0.f, bs = 0.f;
#pragma unroll 4
    for (int k = 0; k < 64; ++k) {
        float sk = __shfl(sval, k);
        as += sk * W1_0[k*64 + lane];
        bs += sk * Wsc0[k*64 + lane];
    }
    float* xsrow = XS + n*192;
    float* scrow = SC + n*192;
    xsrow[lane] = as * 0.125f;
    scrow[lane] = bs * 0.125f;

    float selv = lo ? vx : vz;
    int srcbase = lane & 32;                   // hi lanes source vz from 32..63
    float aP=0.f, aQ=0.f, bP=0.f, bQ=0.f;
#pragma unroll 4
    for (int u = 0; u < 32; ++u) {
        float su = __shfl(selv, u | srcbase);
        float sy = __shfl(vy, u);
        float wa = W1_1[u*32 + u_];
        float wb = Wsc1[u*32 + u_];
        aP += su*wa; aQ += sy*wa;
        bP += su*wb; bQ += sy*wb;
    }
    const float is32 = 0.17677669529663687f;
    if (lo) {
        xsrow[64 + u_*4 + 0] = aP * is32;
        xsrow[64 + u_*4 + 1] = aQ * is32;
        scrow[64 + u_*4 + 0] = bP * is32;
        scrow[64 + u_*4 + 1] = bQ * is32;
    } else {
        xsrow[64 + u_*4 + 2] = aP * is32;
        scrow[64 + u_*4 + 2] = bP * is32;
    }
}

// ---------------------------------------------------------------------------
// K2: per-src edge lists. Only int atomics (400k).
// ---------------------------------------------------------------------------
__global__ __launch_bounds__(256) void k_build_lists(
    const int* __restrict__ ei, int* __restrict__ CNT, int* __restrict__ LIST)
{
    int e = blockIdx.x * 256 + threadIdx.x;
    if (e >= N_EDGES) return;
    int src = ei[e];
    int pos = atomicAdd(&CNT[src], 1);
    if (pos < 64) LIST[src*64 + pos] = e;
}

// ---------------------------------------------------------------------------
// K3: edge MLP via fp16 MFMA, BARRIER-FREE wave-per-16-edges. Layer-1 B-frag
// comes straight from eat into registers (q==0 lanes, coalesced) — no avb, no
// __syncthreads. Output in TP-packed WP layout (dwords):
//   WP[e][j]     = (w0[j] , w1[j])  halves   j=0..63
//   WP[e][64+u]  = (w2[u] , w3[u])  u=0..31  | (w4[u-32], w3[u-32]) u=32..63
// built from paired layer-3 tiles (nt,nt+4)/(8,10)(9,11)(12,10)(13,11) which
// share b-fragments — zero extra MFMA. LDS 18 KB; launch_bounds(256,4).
// ---------------------------------------------------------------------------
__global__ __launch_bounds__(256, 4) void k_edge_mlp(
    const float* __restrict__ eat,
    const _Float16* __restrict__ gA1, const _Float16* __restrict__ gA2,
    const _Float16* __restrict__ gA3,
    uint* __restrict__ WP)
{
    __shared__ _Float16 h1b[64*72];     //  9 KB (wave-private rows)
    __shared__ _Float16 h2b[64*72];     //  9 KB

    const int tid = threadIdx.x;
    const int lane = tid & 63, wv = tid >> 6;
    const int q = lane >> 4, col = lane & 15;
    const int erow = wv*16 + col;
    const int ecol = blockIdx.x*64 + erow;   // this lane's edge (grid exact: no tail)

    const float IS8 = 0.35355339059327373f;  // 1/sqrt(8)

    // ---- layer-1 B fragment from registers ----
    f16x8 b1;
#pragma unroll
    for (int j = 0; j < 8; ++j) b1[j] = (_Float16)0.f;
    if (q == 0) {
        float4 v0 = *(const float4*)(eat + (size_t)ecol*8);
        float4 v1 = *(const float4*)(eat + (size_t)ecol*8 + 4);
        b1[0]=(_Float16)v0.x; b1[1]=(_Float16)v0.y; b1[2]=(_Float16)v0.z; b1[3]=(_Float16)v0.w;
        b1[4]=(_Float16)v1.x; b1[5]=(_Float16)v1.y; b1[6]=(_Float16)v1.z; b1[7]=(_Float16)v1.w;
    }
    // ---- layer 1: 8 -> 64 (K zero-padded to 32), silu ----
#pragma unroll
    for (int nt = 0; nt < 4; ++nt) {
        f32x4 acc = {0.f,0.f,0.f,0.f};
        f16x8 a = *(const f16x8*)&gA1[(nt*64 + lane)*8];
        acc = __builtin_amdgcn_mfma_f32_16x16x32_f16(a, b1, acc, 0, 0, 0);
        f16x4 p;
#pragma unroll
        for (int r = 0; r < 4; ++r) p[r] = (_Float16)silu_f(acc[r]*IS8);
        *(f16x4*)&h1b[erow*72 + nt*16 + q*4] = p;
    }
    // ---- layer 2: 64 -> 64, silu ----
#pragma unroll
    for (int nt = 0; nt < 4; ++nt) {
        f32x4 acc = {0.f,0.f,0.f,0.f};
#pragma unroll
        for (int ks = 0; ks < 2; ++ks) {
            f16x8 a = *(const f16x8*)&gA2[((ks*4+nt)*64 + lane)*8];
            f16x8 b = *(const f16x8*)&h1b[erow*72 + ks*32 + q*8];
            acc = __builtin_amdgcn_mfma_f32_16x16x32_f16(a, b, acc, 0, 0, 0);
        }
        f16x4 p;
#pragma unroll
        for (int r = 0; r < 4; ++r) p[r] = (_Float16)silu_f(acc[r]*0.125f);
        *(f16x4*)&h2b[erow*72 + nt*16 + q*4] = p;
    }
    // ---- layer 3: paired tiles -> packed WP dwords ----
    uint* wpE = WP + (size_t)ecol*128;
    auto tileAcc = [&](int nt) -> f32x4 {
        f32x4 acc = {0.f,0.f,0.f,0.f};
#pragma unroll
        for (int ks = 0; ks < 2; ++ks) {
            f16x8 a = *(const f16x8*)&gA3[((ks*14+nt)*64 + lane)*8];
            f16x8 b = *(const f16x8*)&h2b[erow*72 + ks*32 + q*8];
            acc = __builtin_amdgcn_mfma_f32_16x16x32_f16(a, b, acc, 0, 0, 0);
        }
        return acc;
    };
    auto packStore = [&](f32x4 A, f32x4 B, int baseIdx) {
        uint d[4];
#pragma unroll
        for (int r = 0; r < 4; ++r) {
            __half2 h = __floats2half2_rn(A[r]*0.125f, B[r]*0.125f);
            d[r] = *(uint*)&h;
        }
        *(uint4*)&wpE[baseIdx + q*4] = make_uint4(d[0], d[1], d[2], d[3]);
    };
    f32x4 t10 = tileAcc(10);
    f32x4 t11 = tileAcc(11);
    packStore(tileAcc(0),  tileAcc(4),  0);   // (w0,w1) j = 0..15  slice
    packStore(tileAcc(1),  tileAcc(5),  16);
    packStore(tileAcc(2),  tileAcc(6),  32);
    packStore(tileAcc(3),  tileAcc(7),  48);
    packStore(tileAcc(8),  t10,         64);  // (w2,w3) u = 0..15
    packStore(tileAcc(9),  t11,         80);  // (w2,w3) u = 16..31
    packStore(tileAcc(12), t10,         96);  // (w4,w3) u = 0..15
    packStore(tileAcc(13), t11,        112);  // (w4,w3) u = 16..31
}

// ---------------------------------------------------------------------------
// K4: TWO waves per node (even/odd edges) — halves serial depth, doubles TLP
// (50k waves). Per edge: 2 coalesced dword w-loads (packed WP) + sd + vv + sh.
// Partials combined in LDS; epilogue split: half0 = scalar GEMM+RMS,
// half1 = vector GEMM+RMS.
// ---------------------------------------------------------------------------
struct Pref { float4 sh, vv; float sd; uint wa, wb; };

__device__ __forceinline__ void preload(
    Pref& P, int e, int dst,
    const float* __restrict__ esh, const uint* __restrict__ WP,
    const float* __restrict__ XS, int lane, int u_)
{
    P.sh = *(const float4*)(esh + (size_t)e*4);
    const uint* wp = WP + (size_t)e*128;
    P.wa = wp[lane];
    P.wb = wp[64 + lane];
    const float* xd = XS + (size_t)dst*192;
    P.sd = xd[lane];
    P.vv = *(const float4*)(xd + 64 + u_*4);
}

__global__ __launch_bounds__(256) void k_aggregate(
    const int* __restrict__ ei, const float* __restrict__ esh,
    const uint* __restrict__ WP, const float* __restrict__ XS,
    const float* __restrict__ SC, const int* __restrict__ CNT,
    const int* __restrict__ LIST,
    const float* __restrict__ W2_0, const float* __restrict__ W2_1,
    const float* __restrict__ g0, const float* __restrict__ g1,
    float* __restrict__ out)
{
    __shared__ float aSb[2][2][96];     // [node2][half][row]
    __shared__ float aVb[2][2][392];    // [node2][half][c*130 + row]
    int tid = threadIdx.x;
    int lane = tid & 63, wv = tid >> 6;
    int n2 = wv >> 1, half = wv & 1;
    int n = blockIdx.x*2 + n2;          // grid exact: always < N_NODES
    int u_ = lane & 31;
    bool lo = lane < 32;

    int cnt; { int c = CNT[n]; cnt = c > 64 ? 64 : c; }
    const int* edst = ei + N_EDGES;

    int e_l = 0, dst_l = 0;
    if (cnt > 0) {
        int li = lane < cnt ? lane : cnt - 1;
        e_l = LIST[n*64 + li];
        dst_l = edst[e_l];
    }

    float accM0=0, aV0x=0, aV0y=0, aV0z=0, accM1=0, a12x=0, a12y=0, a12z=0;

    Pref P;
    int i = half;
    if (i < cnt) preload(P, __shfl(e_l,i), __shfl(dst_l,i), esh, WP, XS, lane, u_);
#pragma unroll 1
    for (; i < cnt; i += 2) {
        Pref cur = P;
        int nx = i + 2;
        if (nx < cnt) preload(P, __shfl(e_l,nx), __shfl(dst_l,nx), esh, WP, XS, lane, u_);
        float2 f01 = __half22float2(*(const __half2*)&cur.wa);  // (w0, w1)
        float2 fAB = __half22float2(*(const __half2*)&cur.wb);  // (w2|w4, w3)
        accM0 += f01.x*cur.sd*cur.sh.x;                          // m0
        float t1 = f01.y*cur.sd;                                 // mv0
        aV0x += t1*cur.sh.y; aV0y += t1*cur.sh.z; aV0z += t1*cur.sh.w;
        if (lo) {
            accM1 += fAB.y*(cur.vv.x*cur.sh.y + cur.vv.y*cur.sh.z + cur.vv.z*cur.sh.w); // m1
            a12x += fAB.x*cur.vv.x*cur.sh.x;                     // mv1
            a12y += fAB.x*cur.vv.y*cur.sh.x;
            a12z += fAB.x*cur.vv.z*cur.sh.x;
        } else {                                                 // mv2: w4*cross(vd,sh1)
            a12x += fAB.x*(cur.vv.y*cur.sh.w - cur.vv.z*cur.sh.z);
            a12y += fAB.x*(cur.vv.z*cur.sh.y - cur.vv.x*cur.sh.w);
            a12z += fAB.x*(cur.vv.x*cur.sh.z - cur.vv.y*cur.sh.y);
        }
    }

    const float SEG = 0.25f;                    // 1/sqrt(16)
    const float IS3 = 0.5773502691896258f;      // 1/sqrt(3)
    const float IS2 = 0.7071067811865476f;      // 1/sqrt(2)
    aSb[n2][half][lane] = accM0 * SEG;
    aVb[n2][half][0*130 + lane] = aV0x * SEG;
    aVb[n2][half][1*130 + lane] = aV0y * SEG;
    aVb[n2][half][2*130 + lane] = aV0z * SEG;
    if (lo) {
        aSb[n2][half][64 + u_] = accM1 * SEG * IS3;
        aVb[n2][half][0*130 + 64 + u_] = a12x * SEG;
        aVb[n2][half][1*130 + 64 + u_] = a12y * SEG;
        aVb[n2][half][2*130 + 64 + u_] = a12z * SEG;
    } else {
        aVb[n2][half][0*130 + 96 + u_] = a12x * SEG * IS2;
        aVb[n2][half][1*130 + 96 + u_] = a12y * SEG * IS2;
        aVb[n2][half][2*130 + 96 + u_] = a12z * SEG * IS2;
    }
    __syncthreads();

    if (half == 0) {
        // combine scalar partials (same-wave write->read, lgkmcnt-ordered)
        aSb[n2][0][lane] += aSb[n2][1][lane];
        if (lo) aSb[n2][0][64 + u_] += aSb[n2][1][64 + u_];

        // out_s = ns @ W2_0 / sqrt(96) + sc_s
        float o0=0,o1=0,o2=0,o3=0;
#pragma unroll 4
        for (int k = 0; k < 96; k += 4) {
            o0 += aSb[n2][0][k+0] * W2_0[(k+0)*64 + lane];
            o1 += aSb[n2][0][k+1] * W2_0[(k+1)*64 + lane];
            o2 += aSb[n2][0][k+2] * W2_0[(k+2)*64 + lane];
            o3 += aSb[n2][0][k+3] * W2_0[(k+3)*64 + lane];
        }
        float os = (o0+o1)+(o2+o3);
        const float IS96 = 0.10206207261596575f;  // 1/sqrt(96)
        os = os*IS96 + SC[n*192 + lane];

        float r = os*os;
#pragma unroll
        for (int off = 32; off > 0; off >>= 1) r += __shfl_xor(r, off);
        float rms_s = sqrtf(r*(1.0f/64.0f) + EPS_F);
        out[(size_t)n*160 + lane] = os / rms_s * g0[lane];
    } else {
        // combine vector partials
        for (int idx = lane; idx < 392; idx += 64)
            aVb[n2][0][idx] += aVb[n2][1][idx];

        // out_v[v][c] = sum_u nv[u][c] * W2_1[u][v] / sqrt(128) + sc_v
        int coff = lo ? 0 : 2*130;
        float p0=0,p1=0,q0=0,q1=0;
#pragma unroll 4
        for (int u = 0; u < 128; u += 2) {
            float wv0 = W2_1[(u+0)*32 + u_];
            float wv1 = W2_1[(u+1)*32 + u_];
            p0 += aVb[n2][0][coff + u+0]*wv0;  q0 += aVb[n2][0][130 + u+0]*wv0;
            p1 += aVb[n2][0][coff + u+1]*wv1;  q1 += aVb[n2][0][130 + u+1]*wv1;
        }
        float ov0 = p0+p1, ov1 = q0+q1;
        const float IS128 = 0.08838834764831845f; // 1/sqrt(128)
        float4 scv = *(const float4*)(SC + n*192 + 64 + u_*4);
        float x0 = ov0*IS128 + (lo ? scv.x : scv.z);
        float x1 = ov1*IS128 + scv.y;

        float rv = lo ? (x0*x0 + x1*x1) : (x0*x0);
#pragma unroll
        for (int off = 32; off > 0; off >>= 1) rv += __shfl_xor(rv, off);
        float rms_v = sqrtf(rv*(1.0f/32.0f) + EPS_F);

        float* orow = out + (size_t)n*160;
        float gv = g1[u_] / rms_v;
        if (lo) {
            orow[64 + u_*3 + 0] = x0 * gv;
            orow[64 + u_*3 + 1] = x1 * gv;
        } else {
            orow[64 + u_*3 + 2] = x0 * gv;
        }
    }
}

// ---------------------------------------------------------------------------
extern "C" void kernel_launch(void* const* d_in, const int* in_sizes, int n_in,
                              void* d_out, int out_size, void* d_ws, size_t ws_size,
                              hipStream_t stream)
{
    const float* nh   = (const float*)d_in[0];
    const int*   ei   = (const int*)  d_in[1];
    const float* esh  = (const float*)d_in[2];
    const float* eat  = (const float*)d_in[3];
    const float* W1_0 = (const float*)d_in[4];
    const float* W1_1 = (const float*)d_in[5];
    const float* Wfc1 = (const float*)d_in[6];
    const float* Wfc2 = (const float*)d_in[7];
    const float* Wfc3 = (const float*)d_in[8];
    const float* W2_0 = (const float*)d_in[9];
    const float* W2_1 = (const float*)d_in[10];
    const float* Wsc0 = (const float*)d_in[11];
    const float* Wsc1 = (const float*)d_in[12];
    const float* g0   = (const float*)d_in[13];
    const float* g1   = (const float*)d_in[14];
    float* out = (float*)d_out;

    // workspace layout — ~250 MB
    char* base = (char*)d_ws;
    float*    XS   = (float*)base;                             // N*192 f32   19.2 MB
    float*    SC   = XS + (size_t)N_NODES*192;                 // N*192 f32   19.2 MB
    uint*     WP   = (uint*)(SC + (size_t)N_NODES*192);        // E*128 u32  204.8 MB
    _Float16* gA1  = (_Float16*)(WP + (size_t)N_EDGES*128);    // 2048 f16
    _Float16* gA2  = gA1 + 2048;                               // 4096 f16
    _Float16* gA3  = gA2 + 4096;                               // 14336 f16
    int*      CNT  = (int*)(gA3 + 14336);                      // N int
    int*      LIST = CNT + N_NODES;                            // N*64 int     6.4 MB

    hipMemsetAsync(CNT, 0, N_NODES*sizeof(int), stream);
    k_prepack   <<<10, 256, 0, stream>>>(Wfc1, Wfc2, Wfc3, gA1, gA2, gA3);
    k_node_pre  <<<(N_NODES+3)/4, 256, 0, stream>>>(nh, W1_0, W1_1, Wsc0, Wsc1, XS, SC);
    k_build_lists<<<(N_EDGES+255)/256, 256, 0, stream>>>(ei, CNT, LIST);
    k_edge_mlp  <<<N_EDGES/64, 256, 0, stream>>>(eat, gA1, gA2, gA3, WP);
    k_aggregate <<<N_NODES/2, 256, 0, stream>>>(ei, esh, WP, XS, SC, CNT, LIST,
                                                W2_0, W2_1, g0, g1, out);
}